// Round 1
// baseline (3359.008 us; speedup 1.0000x reference)
//
#include <hip/hip_runtime.h>
#include <hip/hip_bf16.h>
#include <math.h>

#define N_PTS 20000
#define C_IN 128
#define C_OUT 64
#define M_PTS (N_PTS*8)
#define EPS 1e-5f

__device__ __forceinline__ float bf_lo(unsigned int u){ return __uint_as_float(u << 16); }
__device__ __forceinline__ float bf_hi(unsigned int u){ return __uint_as_float(u & 0xffff0000u); }
__device__ __forceinline__ ushort f2bf(float f){
    unsigned int i = __float_as_uint(f);
    unsigned int r = i + 0x7fffu + ((i >> 16) & 1u);
    return (ushort)(r >> 16);
}
__device__ __forceinline__ float silu(float z){ return z / (1.f + expf(-z)); }

// ---------------- GroupNorm1 stats: 32 groups x 4 channels over N_PTS ----------------
__global__ void gn1_stats(const float* __restrict__ x, float* __restrict__ stats){
    int g = blockIdx.x;
    int cbase = g * 4;
    float sum = 0.f, sq = 0.f;
    for (int p = threadIdx.x; p < N_PTS; p += 256){
        float4 v = *(const float4*)(x + (size_t)p * C_IN + cbase);
        sum += v.x + v.y + v.z + v.w;
        sq  += v.x*v.x + v.y*v.y + v.z*v.z + v.w*v.w;
    }
    __shared__ float ls[256], lq[256];
    ls[threadIdx.x] = sum; lq[threadIdx.x] = sq; __syncthreads();
    for (int st = 128; st > 0; st >>= 1){
        if (threadIdx.x < st){ ls[threadIdx.x] += ls[threadIdx.x+st]; lq[threadIdx.x] += lq[threadIdx.x+st]; }
        __syncthreads();
    }
    if (threadIdx.x == 0){
        float mu = ls[0] / (N_PTS * 4.0f);
        float var = lq[0] / (N_PTS * 4.0f) - mu * mu;
        stats[g] = mu; stats[32 + g] = rsqrtf(var + EPS);
    }
}

// ---------------- h = silu(gn1(x)) -> bf16 ----------------
__global__ void h_compute(const float* __restrict__ x, const float* __restrict__ stats,
                          const float* __restrict__ gg, const float* __restrict__ gb,
                          ushort* __restrict__ h){
    int i = blockIdx.x * 256 + threadIdx.x;
    if (i >= N_PTS * C_IN) return;
    int c = i & (C_IN - 1);
    int g = c >> 2;
    float z = (x[i] - stats[g]) * stats[32 + g] * gg[c] + gb[c];
    h[i] = f2bf(silu(z));
}

// ---------------- parent occupancy grid ----------------
__global__ void pg_init(int* __restrict__ pg){
    int i = blockIdx.x * 256 + threadIdx.x;
    if (i < 32768) pg[i] = -1;
}
__global__ void pg_scatter(const int* __restrict__ coords, int* __restrict__ pg){
    int i = blockIdx.x * 256 + threadIdx.x;
    if (i >= N_PTS) return;
    const int* cd = coords + i * 4;
    pg[(cd[1] * 32 + cd[2]) * 32 + cd[3]] = i;
}

// ---------------- skip: s = x @ Ws + bs  (N_PTS x 64) ----------------
__global__ void __launch_bounds__(256) skip_kernel(const float* __restrict__ x,
                                                   const float* __restrict__ Wsk,
                                                   const float* __restrict__ bsk,
                                                   float* __restrict__ s){
    __shared__ float w[C_IN * C_OUT];
    for (int j = threadIdx.x; j < C_IN * C_OUT; j += 256) w[j] = Wsk[j];
    __syncthreads();
    int co = threadIdx.x & 63, pr = threadIdx.x >> 6;
    int p = blockIdx.x * 4 + pr;
    const float* xr = x + (size_t)p * C_IN;
    float a = bsk[co];
    for (int cb = 0; cb < C_IN; cb += 4){
        float4 v = *(const float4*)(xr + cb);
        a += v.x * w[(cb+0)*64+co] + v.y * w[(cb+1)*64+co]
           + v.z * w[(cb+2)*64+co] + v.w * w[(cb+3)*64+co];
    }
    s[(size_t)p * C_OUT + co] = a;
}

// ---------------- sparse subm conv, 27 taps, CIN -> 64 ----------------
// block = 256 threads = 32 co-threads (each handles co, co+32) x 8 point-rows x 4 points
template<int CIN>
__global__ void __launch_bounds__(256) conv_kernel(
    const ushort* __restrict__ feat, const int* __restrict__ pg,
    const int* __restrict__ coords, const float* __restrict__ W,
    const float* __restrict__ bias, const float* __restrict__ skip,
    float* __restrict__ out, int child_feat)
{
    __shared__ float wlds[CIN * 64];
    const int cot = threadIdx.x & 31;
    const int pr  = threadIdx.x >> 5;
    const int mbase = blockIdx.x * 32 + pr * 4;
    float acc[4][2];
#pragma unroll
    for (int i = 0; i < 4; i++){ acc[i][0] = 0.f; acc[i][1] = 0.f; }

    for (int t = 0; t < 27; t++){
        __syncthreads();
        for (int j = threadIdx.x; j < CIN * 64; j += 256) wlds[j] = W[t * CIN * 64 + j];
        __syncthreads();
        const int dx = t / 9 - 1, dy = (t / 3) % 3 - 1, dz = t % 3 - 1;
#pragma unroll
        for (int pi = 0; pi < 4; pi++){
            const int m = mbase + pi;
            const int parent = m >> 3, o = m & 7;
            const int* cd = coords + parent * 4;
            const int cx = 2 * cd[1] + ((o >> 2) & 1) + dx;
            const int cy = 2 * cd[2] + ((o >> 1) & 1) + dy;
            const int cz = 2 * cd[3] + (o & 1) + dz;
            if ((unsigned)cx >= 64u || (unsigned)cy >= 64u || (unsigned)cz >= 64u) continue;
            const int pidx = pg[((cx >> 1) * 32 + (cy >> 1)) * 32 + (cz >> 1)];
            if (pidx < 0) continue;
            const size_t row = child_feat ? (size_t)(pidx * 8 + (((cx & 1) << 2) | ((cy & 1) << 1) | (cz & 1)))
                                          : (size_t)pidx;
            const ushort* hr = feat + row * CIN;
            float a0 = acc[pi][0], a1 = acc[pi][1];
#pragma unroll
            for (int cb = 0; cb < CIN; cb += 8){
                uint4 pk = *(const uint4*)(hr + cb);
                const float* wp = wlds + cb * 64 + cot;
                float f;
                f = bf_lo(pk.x); a0 += f * wp[0];   a1 += f * wp[32];
                f = bf_hi(pk.x); a0 += f * wp[64];  a1 += f * wp[96];
                f = bf_lo(pk.y); a0 += f * wp[128]; a1 += f * wp[160];
                f = bf_hi(pk.y); a0 += f * wp[192]; a1 += f * wp[224];
                f = bf_lo(pk.z); a0 += f * wp[256]; a1 += f * wp[288];
                f = bf_hi(pk.z); a0 += f * wp[320]; a1 += f * wp[352];
                f = bf_lo(pk.w); a0 += f * wp[384]; a1 += f * wp[416];
                f = bf_hi(pk.w); a0 += f * wp[448]; a1 += f * wp[480];
            }
            acc[pi][0] = a0; acc[pi][1] = a1;
        }
    }
#pragma unroll
    for (int pi = 0; pi < 4; pi++){
        const int m = mbase + pi;
        const int parent = m >> 3;
        float b0 = bias[cot], b1v = bias[cot + 32];
        if (skip){
            b0  += skip[(size_t)parent * C_OUT + cot];
            b1v += skip[(size_t)parent * C_OUT + cot + 32];
        }
        out[(size_t)m * C_OUT + cot]      = acc[pi][0] + b0;
        out[(size_t)m * C_OUT + cot + 32] = acc[pi][1] + b1v;
    }
}

// ---------------- GroupNorm2 stats: 32 groups x 2 channels over M_PTS ----------------
__global__ void gn2_stats(const float* __restrict__ hf1, float* __restrict__ stats){
    int g = blockIdx.x;
    int cbase = g * 2;
    float sum = 0.f, sq = 0.f;
    for (int p = threadIdx.x; p < M_PTS; p += 256){
        float2 v = *(const float2*)(hf1 + (size_t)p * C_OUT + cbase);
        sum += v.x + v.y;
        sq  += v.x*v.x + v.y*v.y;
    }
    __shared__ float ls[256], lq[256];
    ls[threadIdx.x] = sum; lq[threadIdx.x] = sq; __syncthreads();
    for (int st = 128; st > 0; st >>= 1){
        if (threadIdx.x < st){ ls[threadIdx.x] += ls[threadIdx.x+st]; lq[threadIdx.x] += lq[threadIdx.x+st]; }
        __syncthreads();
    }
    if (threadIdx.x == 0){
        float mu = ls[0] / (M_PTS * 2.0f);
        float var = lq[0] / (M_PTS * 2.0f) - mu * mu;
        stats[g] = mu; stats[32 + g] = rsqrtf(var + EPS);
    }
}

// ---------------- h2 = silu(gn2(hf1)) -> bf16 ----------------
__global__ void h2_compute(const float* __restrict__ hf1, const float* __restrict__ stats,
                           const float* __restrict__ gg, const float* __restrict__ gb,
                           ushort* __restrict__ h2){
    int i = blockIdx.x * 256 + threadIdx.x;
    if (i >= M_PTS * C_OUT) return;
    int c = i & (C_OUT - 1);
    int g = c >> 1;
    float z = (hf1[i] - stats[g]) * stats[32 + g] * gg[c] + gb[c];
    h2[i] = f2bf(silu(z));
}

extern "C" void kernel_launch(void* const* d_in, const int* in_sizes, int n_in,
                              void* d_out, int out_size, void* d_ws, size_t ws_size,
                              hipStream_t stream){
    const float* x   = (const float*)d_in[0];
    const int*   cds = (const int*)  d_in[1];
    const float* g1  = (const float*)d_in[2];
    const float* b1  = (const float*)d_in[3];
    const float* W1  = (const float*)d_in[4];
    const float* bb1 = (const float*)d_in[5];
    const float* g2  = (const float*)d_in[6];
    const float* b2  = (const float*)d_in[7];
    const float* W2  = (const float*)d_in[8];
    const float* bb2 = (const float*)d_in[9];
    const float* Wsk = (const float*)d_in[10];
    const float* bsk = (const float*)d_in[11];
    float* out = (float*)d_out;
    char* ws = (char*)d_ws;

    // workspace layout (all offsets 256B-aligned)
    float*  stats1 = (float*) (ws);              // 64 f32
    float*  stats2 = (float*) (ws + 256);        // 64 f32
    int*    pg     = (int*)   (ws + 512);        // 32768 i32 -> ends 131584
    ushort* h      = (ushort*)(ws + 131584);     // N*C bf16   (5,120,000 B)
    ushort* h2     = (ushort*)(ws + 5251584);    // M*CO bf16  (20,480,000 B)
    float*  s      = (float*) (ws + 25731584);   // N*CO f32   (5,120,000 B)
    // total ws use: 30,851,584 B. hf1 (fp32, M*CO) lives in d_out between conv1 and h2_compute.

    gn1_stats<<<32, 256, 0, stream>>>(x, stats1);
    h_compute<<<(N_PTS * C_IN + 255) / 256, 256, 0, stream>>>(x, stats1, g1, b1, h);
    pg_init<<<128, 256, 0, stream>>>(pg);
    pg_scatter<<<(N_PTS + 255) / 256, 256, 0, stream>>>(cds, pg);
    skip_kernel<<<N_PTS / 4, 256, 0, stream>>>(x, Wsk, bsk, s);
    conv_kernel<C_IN><<<M_PTS / 32, 256, 0, stream>>>(h, pg, cds, W1, bb1, nullptr, out, 0);
    gn2_stats<<<32, 256, 0, stream>>>(out, stats2);
    h2_compute<<<(M_PTS * C_OUT + 255) / 256, 256, 0, stream>>>(out, stats2, g2, b2, h2);
    conv_kernel<C_OUT><<<M_PTS / 32, 256, 0, stream>>>(h2, pg, cds, W2, bb2, s, out, 1);
}

// Round 2
// 633.399 us; speedup vs baseline: 5.3031x; 5.3031x over previous
//
#include <hip/hip_runtime.h>
#include <hip/hip_bf16.h>
#include <math.h>

#define N_PTS 20000
#define C_IN 128
#define C_OUT 64
#define M_PTS (N_PTS*8)
#define EPS 1e-5f

typedef __attribute__((ext_vector_type(8))) short short8;
typedef __attribute__((ext_vector_type(4))) float float4v;

__device__ __forceinline__ ushort f2bf(float f){
    unsigned int i = __float_as_uint(f);
    unsigned int r = i + 0x7fffu + ((i >> 16) & 1u);
    return (ushort)(r >> 16);
}
__device__ __forceinline__ float silu(float z){ return z / (1.f + expf(-z)); }

// ---------------- GroupNorm1 stats: 32 groups x 4 channels over N_PTS ----------------
__global__ void gn1_stats(const float* __restrict__ x, float* __restrict__ stats){
    int g = blockIdx.x;
    int cbase = g * 4;
    float sum = 0.f, sq = 0.f;
    for (int p = threadIdx.x; p < N_PTS; p += 256){
        float4 v = *(const float4*)(x + (size_t)p * C_IN + cbase);
        sum += v.x + v.y + v.z + v.w;
        sq  += v.x*v.x + v.y*v.y + v.z*v.z + v.w*v.w;
    }
    __shared__ float ls[256], lq[256];
    ls[threadIdx.x] = sum; lq[threadIdx.x] = sq; __syncthreads();
    for (int st = 128; st > 0; st >>= 1){
        if (threadIdx.x < st){ ls[threadIdx.x] += ls[threadIdx.x+st]; lq[threadIdx.x] += lq[threadIdx.x+st]; }
        __syncthreads();
    }
    if (threadIdx.x == 0){
        float mu = ls[0] / (N_PTS * 4.0f);
        float var = lq[0] / (N_PTS * 4.0f) - mu * mu;
        stats[g] = mu; stats[32 + g] = rsqrtf(var + EPS);
    }
}

// ---------------- h = silu(gn1(x)) -> bf16 ----------------
__global__ void h_compute(const float* __restrict__ x, const float* __restrict__ stats,
                          const float* __restrict__ gg, const float* __restrict__ gb,
                          ushort* __restrict__ h){
    int i = blockIdx.x * 256 + threadIdx.x;
    if (i >= N_PTS * C_IN) return;
    int c = i & (C_IN - 1);
    int g = c >> 2;
    float z = (x[i] - stats[g]) * stats[32 + g] * gg[c] + gb[c];
    h[i] = f2bf(silu(z));
}

// ---------------- parent occupancy grid ----------------
__global__ void pg_init(int* __restrict__ pg){
    int i = blockIdx.x * 256 + threadIdx.x;
    if (i < 32768) pg[i] = -1;
}
__global__ void pg_scatter(const int* __restrict__ coords, int* __restrict__ pg){
    int i = blockIdx.x * 256 + threadIdx.x;
    if (i >= N_PTS) return;
    const int* cd = coords + i * 4;
    pg[(cd[1] * 32 + cd[2]) * 32 + cd[3]] = i;
}

// ---------------- weight prep: W[t][ci][co] f32 -> Wt[t][co][ci] bf16 ----------------
__global__ void wprep(const float* __restrict__ W, ushort* __restrict__ Wt, int cin){
    int idx = blockIdx.x * 256 + threadIdx.x;
    if (idx >= 27 * cin * 64) return;
    int t = idx / (cin * 64);
    int rem = idx - t * cin * 64;
    int co = rem / cin;
    int ci = rem - co * cin;
    Wt[idx] = f2bf(W[(t * cin + ci) * 64 + co]);
}

// ---------------- skip: s = x @ Ws + bs  (N_PTS x 64) ----------------
__global__ void __launch_bounds__(256) skip_kernel(const float* __restrict__ x,
                                                   const float* __restrict__ Wsk,
                                                   const float* __restrict__ bsk,
                                                   float* __restrict__ s){
    __shared__ float w[C_IN * C_OUT];
    for (int j = threadIdx.x; j < C_IN * C_OUT; j += 256) w[j] = Wsk[j];
    __syncthreads();
    int co = threadIdx.x & 63, pr = threadIdx.x >> 6;
    int p = blockIdx.x * 4 + pr;
    const float* xr = x + (size_t)p * C_IN;
    float a = bsk[co];
    for (int cb = 0; cb < C_IN; cb += 4){
        float4 v = *(const float4*)(xr + cb);
        a += v.x * w[(cb+0)*64+co] + v.y * w[(cb+1)*64+co]
           + v.z * w[(cb+2)*64+co] + v.w * w[(cb+3)*64+co];
    }
    s[(size_t)p * C_OUT + co] = a;
}

__device__ __forceinline__ int nbr_row(int cx, int cy, int cz,
                                       const int* __restrict__ pg, int child){
    if ((unsigned)cx >= 64u || (unsigned)cy >= 64u || (unsigned)cz >= 64u) return -1;
    int pidx = pg[((cx >> 1) * 32 + (cy >> 1)) * 32 + (cz >> 1)];
    if (pidx < 0) return -1;
    return child ? pidx * 8 + (((cx & 1) << 2) | ((cy & 1) << 1) | (cz & 1)) : pidx;
}

// ---------------- MFMA implicit-GEMM sparse subm conv ----------------
// block = 256 threads (4 waves), M-tile = 128 children, N = 64 co.
// Per tap: gather A (128 x CIN bf16) + weight tile (co-major) into LDS, MFMA.
// CHILD=0: feature row = parent idx (conv1). CHILD=1: row = pidx*8+off (conv2, +skip).
template<int CIN, int CHILD>
__global__ void __launch_bounds__(256) conv_mfma(
    const ushort* __restrict__ feat, const int* __restrict__ pg,
    const int* __restrict__ coords, const ushort* __restrict__ Wt,
    const float* __restrict__ bias, const float* __restrict__ skip,
    float* __restrict__ out)
{
    constexpr int AS = CIN + 8;              // +16B pad: rows 16B-aligned, 2-way banks (free)
    __shared__ ushort aT[128 * AS];
    __shared__ ushort bT[64 * AS];
    __shared__ int rowIdx[2][128];

    const int tid = threadIdx.x;
    const int mbase = blockIdx.x * 128;

    // per-point child coords live in registers of threads 0..127
    int cx0 = 0, cy0 = 0, cz0 = 0;
    if (tid < 128){
        int m = mbase + tid, p = m >> 3, o = m & 7;
        const int* cd = coords + p * 4;
        cx0 = 2 * cd[1] + ((o >> 2) & 1);
        cy0 = 2 * cd[2] + ((o >> 1) & 1);
        cz0 = 2 * cd[3] + (o & 1);
        rowIdx[0][tid] = nbr_row(cx0 - 1, cy0 - 1, cz0 - 1, pg, CHILD);
    }

    float4v acc[2][4];
#pragma unroll
    for (int i = 0; i < 2; i++)
#pragma unroll
        for (int nb = 0; nb < 4; nb++)
#pragma unroll
            for (int rg = 0; rg < 4; rg++) acc[i][nb][rg] = 0.f;

    const int wv = tid >> 6, l = tid & 63;
    const int r16 = l & 15, q = l >> 4;

    for (int t = 0; t < 27; t++){
        __syncthreads();   // rowIdx[t&1] ready; previous tap's MFMA reads done
        // ---- stage B: Wt[t] (64 x CIN, co-major) -> bT ----
        const ushort* wt = Wt + t * 64 * CIN;
#pragma unroll
        for (int it = 0; it < 64 * CIN / 8 / 256; it++){
            int u = it * 256 + tid;
            int co = u / (CIN / 8), sg = u - co * (CIN / 8);
            *(uint4*)&bT[co * AS + sg * 8] = *(const uint4*)&wt[co * CIN + sg * 8];
        }
        // ---- stage A: gather 128 feature rows (zero rows for missing) ----
        const int* rI = rowIdx[t & 1];
#pragma unroll
        for (int it = 0; it < 128 * CIN / 8 / 256; it++){
            int u = it * 256 + tid;
            int r = u / (CIN / 8), sg = u - r * (CIN / 8);
            int row = rI[r];
            uint4 v = {0u, 0u, 0u, 0u};
            if (row >= 0) v = *(const uint4*)&feat[(size_t)row * CIN + sg * 8];
            *(uint4*)&aT[r * AS + sg * 8] = v;
        }
        // ---- compute next tap's gather rows ----
        if (tid < 128 && t + 1 < 27){
            int tn = t + 1;
            int dx = tn / 9 - 1, dy = (tn / 3) % 3 - 1, dz = tn % 3 - 1;
            rowIdx[(t + 1) & 1][tid] = nbr_row(cx0 + dx, cy0 + dy, cz0 + dz, pg, CHILD);
        }
        __syncthreads();   // staging done
        // ---- MFMA: wave wv computes rows [wv*32, wv*32+32) x 64 cols ----
#pragma unroll
        for (int kb = 0; kb < CIN / 32; kb++){
            int ko = kb * 32 + q * 8;
            short8 a0 = *(const short8*)&aT[(wv * 32 +      r16) * AS + ko];
            short8 a1 = *(const short8*)&aT[(wv * 32 + 16 + r16) * AS + ko];
            short8 b0 = *(const short8*)&bT[(      r16) * AS + ko];
            short8 b1 = *(const short8*)&bT[(16 + r16) * AS + ko];
            short8 b2 = *(const short8*)&bT[(32 + r16) * AS + ko];
            short8 b3 = *(const short8*)&bT[(48 + r16) * AS + ko];
            acc[0][0] = __builtin_amdgcn_mfma_f32_16x16x32_bf16(a0, b0, acc[0][0], 0, 0, 0);
            acc[0][1] = __builtin_amdgcn_mfma_f32_16x16x32_bf16(a0, b1, acc[0][1], 0, 0, 0);
            acc[0][2] = __builtin_amdgcn_mfma_f32_16x16x32_bf16(a0, b2, acc[0][2], 0, 0, 0);
            acc[0][3] = __builtin_amdgcn_mfma_f32_16x16x32_bf16(a0, b3, acc[0][3], 0, 0, 0);
            acc[1][0] = __builtin_amdgcn_mfma_f32_16x16x32_bf16(a1, b0, acc[1][0], 0, 0, 0);
            acc[1][1] = __builtin_amdgcn_mfma_f32_16x16x32_bf16(a1, b1, acc[1][1], 0, 0, 0);
            acc[1][2] = __builtin_amdgcn_mfma_f32_16x16x32_bf16(a1, b2, acc[1][2], 0, 0, 0);
            acc[1][3] = __builtin_amdgcn_mfma_f32_16x16x32_bf16(a1, b3, acc[1][3], 0, 0, 0);
        }
    }

    // ---- epilogue: C/D layout col=lane&15, row=(lane>>4)*4+reg ----
#pragma unroll
    for (int i = 0; i < 2; i++)
#pragma unroll
        for (int nb = 0; nb < 4; nb++)
#pragma unroll
            for (int rg = 0; rg < 4; rg++){
                int m = mbase + wv * 32 + i * 16 + q * 4 + rg;
                int co = nb * 16 + r16;
                float v = acc[i][nb][rg] + bias[co];
                if (CHILD) v += skip[(size_t)(m >> 3) * 64 + co];
                out[(size_t)m * 64 + co] = v;
            }
}

// ---------------- GroupNorm2 stats: 32 groups x 2 channels over M_PTS ----------------
__global__ void gn2_stats(const float* __restrict__ hf1, float* __restrict__ stats){
    int g = blockIdx.x;
    int cbase = g * 2;
    float sum = 0.f, sq = 0.f;
    for (int p = threadIdx.x; p < M_PTS; p += 256){
        float2 v = *(const float2*)(hf1 + (size_t)p * C_OUT + cbase);
        sum += v.x + v.y;
        sq  += v.x*v.x + v.y*v.y;
    }
    __shared__ float ls[256], lq[256];
    ls[threadIdx.x] = sum; lq[threadIdx.x] = sq; __syncthreads();
    for (int st = 128; st > 0; st >>= 1){
        if (threadIdx.x < st){ ls[threadIdx.x] += ls[threadIdx.x+st]; lq[threadIdx.x] += lq[threadIdx.x+st]; }
        __syncthreads();
    }
    if (threadIdx.x == 0){
        float mu = ls[0] / (M_PTS * 2.0f);
        float var = lq[0] / (M_PTS * 2.0f) - mu * mu;
        stats[g] = mu; stats[32 + g] = rsqrtf(var + EPS);
    }
}

// ---------------- h2 = silu(gn2(hf1)) -> bf16 ----------------
__global__ void h2_compute(const float* __restrict__ hf1, const float* __restrict__ stats,
                           const float* __restrict__ gg, const float* __restrict__ gb,
                           ushort* __restrict__ h2){
    int i = blockIdx.x * 256 + threadIdx.x;
    if (i >= M_PTS * C_OUT) return;
    int c = i & (C_OUT - 1);
    int g = c >> 1;
    float z = (hf1[i] - stats[g]) * stats[32 + g] * gg[c] + gb[c];
    h2[i] = f2bf(silu(z));
}

extern "C" void kernel_launch(void* const* d_in, const int* in_sizes, int n_in,
                              void* d_out, int out_size, void* d_ws, size_t ws_size,
                              hipStream_t stream){
    const float* x   = (const float*)d_in[0];
    const int*   cds = (const int*)  d_in[1];
    const float* g1  = (const float*)d_in[2];
    const float* b1  = (const float*)d_in[3];
    const float* W1  = (const float*)d_in[4];
    const float* bb1 = (const float*)d_in[5];
    const float* g2  = (const float*)d_in[6];
    const float* b2  = (const float*)d_in[7];
    const float* W2  = (const float*)d_in[8];
    const float* bb2 = (const float*)d_in[9];
    const float* Wsk = (const float*)d_in[10];
    const float* bsk = (const float*)d_in[11];
    float* out = (float*)d_out;
    char* ws = (char*)d_ws;

    // workspace layout (256B-aligned offsets)
    float*  stats1 = (float*) (ws);               // 64 f32
    float*  stats2 = (float*) (ws + 256);         // 64 f32
    int*    pg     = (int*)   (ws + 512);         // 32768 i32 -> ends 131584
    ushort* h      = (ushort*)(ws + 131584);      // N*C bf16   (5,120,000 B)
    ushort* h2     = (ushort*)(ws + 5251584);     // M*CO bf16  (20,480,000 B)
    float*  s      = (float*) (ws + 25731584);    // N*CO f32   (5,120,000 B)
    ushort* Wt1    = (ushort*)(ws + 30851584);    // 27*64*128 bf16 (442,368 B)
    ushort* Wt2    = (ushort*)(ws + 31294208);    // 27*64*64 bf16  (221,184 B)
    // total ws use: 31,515,392 B. hf1 (fp32, M*CO) lives in d_out between conv1 and h2_compute.

    gn1_stats<<<32, 256, 0, stream>>>(x, stats1);
    h_compute<<<(N_PTS * C_IN + 255) / 256, 256, 0, stream>>>(x, stats1, g1, b1, h);
    pg_init<<<128, 256, 0, stream>>>(pg);
    pg_scatter<<<(N_PTS + 255) / 256, 256, 0, stream>>>(cds, pg);
    wprep<<<(27 * C_IN * 64 + 255) / 256, 256, 0, stream>>>(W1, Wt1, C_IN);
    wprep<<<(27 * C_OUT * 64 + 255) / 256, 256, 0, stream>>>(W2, Wt2, C_OUT);
    skip_kernel<<<N_PTS / 4, 256, 0, stream>>>(x, Wsk, bsk, s);
    conv_mfma<C_IN, 0><<<M_PTS / 128, 256, 0, stream>>>(h, pg, cds, Wt1, bb1, nullptr, out);
    gn2_stats<<<32, 256, 0, stream>>>(out, stats2);
    h2_compute<<<(M_PTS * C_OUT + 255) / 256, 256, 0, stream>>>(out, stats2, g2, b2, h2);
    conv_mfma<C_OUT, 1><<<M_PTS / 128, 256, 0, stream>>>(h2, pg, cds, Wt2, bb2, s, out);
}

// Round 4
// 398.741 us; speedup vs baseline: 8.4240x; 1.5885x over previous
//
#include <hip/hip_runtime.h>
#include <hip/hip_bf16.h>
#include <math.h>

#define N_PTS 20000
#define C_IN 128
#define C_OUT 64
#define M_PTS (N_PTS*8)
#define EPS 1e-5f

typedef __attribute__((ext_vector_type(8))) short short8;
typedef __attribute__((ext_vector_type(4))) float float4v;

__device__ __forceinline__ ushort f2bf(float f){
    unsigned int i = __float_as_uint(f);
    unsigned int r = i + 0x7fffu + ((i >> 16) & 1u);
    return (ushort)(r >> 16);
}
__device__ __forceinline__ float silu(float z){ return z / (1.f + expf(-z)); }

// stats layout (fp32, in ws): [0..31] gn1 group sum, [32..63] gn1 group sumsq,
//                             [64..127] gn2 per-channel sum, [128..191] gn2 per-channel sumsq

// ---------------- parent occupancy grid + stats zero-init ----------------
__global__ void pg_init(int* __restrict__ pg, float* __restrict__ stats){
    int i = blockIdx.x * 256 + threadIdx.x;
    if (i < 32768) pg[i] = -1;
    if (i < 192) stats[i] = 0.f;
}
__global__ void pg_scatter(const int* __restrict__ coords, int* __restrict__ pg){
    int i = blockIdx.x * 256 + threadIdx.x;
    if (i >= N_PTS) return;
    const int* cd = coords + i * 4;
    pg[(cd[1] * 32 + cd[2]) * 32 + cd[3]] = i;
}

// ---------------- GN1 partial stats: 512-block grid-stride + atomics ----------------
__global__ void __launch_bounds__(256) gn1_partial(const float* __restrict__ x,
                                                   float* __restrict__ stats){
    __shared__ float ls[64];
    if (threadIdx.x < 64) ls[threadIdx.x] = 0.f;
    __syncthreads();
    const int g = threadIdx.x & 31;           // group (4 channels each)
    const int r0 = blockIdx.x * 8 + (threadIdx.x >> 5);
    float sum = 0.f, sq = 0.f;
    for (int r = r0; r < N_PTS; r += 8 * 512){
        float4 v = *(const float4*)(x + (size_t)r * C_IN + g * 4);
        sum += v.x + v.y + v.z + v.w;
        sq  += v.x*v.x + v.y*v.y + v.z*v.z + v.w*v.w;
    }
    atomicAdd(&ls[g], sum);
    atomicAdd(&ls[32 + g], sq);
    __syncthreads();
    if (threadIdx.x < 64) atomicAdd(&stats[threadIdx.x], ls[threadIdx.x]);
}

// ---------------- h = silu(gn1(x)) -> bf16 (stats finalized inline) ----------------
__global__ void h_compute(const float* __restrict__ x, const float* __restrict__ stats,
                          const float* __restrict__ gg, const float* __restrict__ gb,
                          ushort* __restrict__ h){
    int i = blockIdx.x * 256 + threadIdx.x;
    if (i >= N_PTS * C_IN) return;
    int c = i & (C_IN - 1);
    int g = c >> 2;
    float mu = stats[g] * (1.0f / (N_PTS * 4.0f));
    float var = stats[32 + g] * (1.0f / (N_PTS * 4.0f)) - mu * mu;
    float rs = rsqrtf(var + EPS);
    float z = (x[i] - mu) * rs * gg[c] + gb[c];
    h[i] = f2bf(silu(z));
}

// ---------------- weight prep: W[t][ci][co] f32 -> Wt[t][co][ci] bf16 ----------------
__global__ void wprep(const float* __restrict__ W, ushort* __restrict__ Wt, int cin){
    int idx = blockIdx.x * 256 + threadIdx.x;
    if (idx >= 27 * cin * 64) return;
    int t = idx / (cin * 64);
    int rem = idx - t * cin * 64;
    int co = rem / cin;
    int ci = rem - co * cin;
    Wt[idx] = f2bf(W[(t * cin + ci) * 64 + co]);
}

// ---------------- skip: s = x @ Ws + bs  (N_PTS x 64) ----------------
__global__ void __launch_bounds__(256) skip_kernel(const float* __restrict__ x,
                                                   const float* __restrict__ Wsk,
                                                   const float* __restrict__ bsk,
                                                   float* __restrict__ s){
    __shared__ float w[C_IN * C_OUT];
    for (int j = threadIdx.x; j < C_IN * C_OUT; j += 256) w[j] = Wsk[j];
    __syncthreads();
    int co = threadIdx.x & 63, pr = threadIdx.x >> 6;
    int p = blockIdx.x * 4 + pr;
    const float* xr = x + (size_t)p * C_IN;
    float a = bsk[co];
    for (int cb = 0; cb < C_IN; cb += 4){
        float4 v = *(const float4*)(xr + cb);
        a += v.x * w[(cb+0)*64+co] + v.y * w[(cb+1)*64+co]
           + v.z * w[(cb+2)*64+co] + v.w * w[(cb+3)*64+co];
    }
    s[(size_t)p * C_OUT + co] = a;
}

__device__ __forceinline__ int nbr_row(int cx, int cy, int cz,
                                       const int* __restrict__ pg, int child){
    if ((unsigned)cx >= 64u || (unsigned)cy >= 64u || (unsigned)cz >= 64u) return -1;
    int pidx = pg[((cx >> 1) * 32 + (cy >> 1)) * 32 + (cz >> 1)];
    if (pidx < 0) return -1;
    return child ? pidx * 8 + (((cx & 1) << 2) | ((cy & 1) << 1) | (cz & 1)) : pidx;
}

// ---------------- MFMA implicit-GEMM sparse subm conv ----------------
// block = 256 threads (4 waves), M-tile = 128 children, N = 64 co.
// CHILD=0 (conv1): feature row = parent idx; fused GN2 sum/sumsq accumulation.
// CHILD=1 (conv2): row = pidx*8+off; adds skip.
template<int CIN, int CHILD>
__global__ void __launch_bounds__(256) conv_mfma(
    const ushort* __restrict__ feat, const int* __restrict__ pg,
    const int* __restrict__ coords, const ushort* __restrict__ Wt,
    const float* __restrict__ bias, const float* __restrict__ skip,
    float* __restrict__ out, float* __restrict__ statsAcc)
{
    constexpr int AS = CIN + 8;              // +16B pad: rows 16B-aligned, 2-way banks (free)
    __shared__ ushort aT[128 * AS];
    __shared__ ushort bT[64 * AS];
    __shared__ int rowIdx[2][128];

    const int tid = threadIdx.x;
    const int mbase = blockIdx.x * 128;

    // per-point child coords live in registers of threads 0..127
    int cx0 = 0, cy0 = 0, cz0 = 0;
    if (tid < 128){
        int m = mbase + tid, p = m >> 3, o = m & 7;
        const int* cd = coords + p * 4;
        cx0 = 2 * cd[1] + ((o >> 2) & 1);
        cy0 = 2 * cd[2] + ((o >> 1) & 1);
        cz0 = 2 * cd[3] + (o & 1);
        rowIdx[0][tid] = nbr_row(cx0 - 1, cy0 - 1, cz0 - 1, pg, CHILD);
    }

    float4v acc[2][4];
#pragma unroll
    for (int i = 0; i < 2; i++)
#pragma unroll
        for (int nb = 0; nb < 4; nb++)
#pragma unroll
            for (int rg = 0; rg < 4; rg++) acc[i][nb][rg] = 0.f;

    const int wv = tid >> 6, l = tid & 63;
    const int r16 = l & 15, qd = l >> 4;

    for (int t = 0; t < 27; t++){
        __syncthreads();   // rowIdx[t&1] ready; previous tap's MFMA reads done
        // ---- stage B: Wt[t] (64 x CIN, co-major) -> bT ----
        const ushort* wt = Wt + t * 64 * CIN;
#pragma unroll
        for (int it = 0; it < 64 * CIN / 8 / 256; it++){
            int u = it * 256 + tid;
            int co = u / (CIN / 8), sg = u - co * (CIN / 8);
            *(uint4*)&bT[co * AS + sg * 8] = *(const uint4*)&wt[co * CIN + sg * 8];
        }
        // ---- stage A: gather 128 feature rows (zero rows for missing) ----
        const int* rI = rowIdx[t & 1];
#pragma unroll
        for (int it = 0; it < 128 * CIN / 8 / 256; it++){
            int u = it * 256 + tid;
            int r = u / (CIN / 8), sg = u - r * (CIN / 8);
            int row = rI[r];
            uint4 v = {0u, 0u, 0u, 0u};
            if (row >= 0) v = *(const uint4*)&feat[(size_t)row * CIN + sg * 8];
            *(uint4*)&aT[r * AS + sg * 8] = v;
        }
        // ---- compute next tap's gather rows ----
        if (tid < 128 && t + 1 < 27){
            int tn = t + 1;
            int dx = tn / 9 - 1, dy = (tn / 3) % 3 - 1, dz = tn % 3 - 1;
            rowIdx[(t + 1) & 1][tid] = nbr_row(cx0 + dx, cy0 + dy, cz0 + dz, pg, CHILD);
        }
        __syncthreads();   // staging done
        // ---- MFMA: wave wv computes rows [wv*32, wv*32+32) x 64 cols ----
#pragma unroll
        for (int kb = 0; kb < CIN / 32; kb++){
            int ko = kb * 32 + qd * 8;
            short8 a0 = *(const short8*)&aT[(wv * 32 +      r16) * AS + ko];
            short8 a1 = *(const short8*)&aT[(wv * 32 + 16 + r16) * AS + ko];
            short8 b0 = *(const short8*)&bT[(      r16) * AS + ko];
            short8 b1 = *(const short8*)&bT[(16 + r16) * AS + ko];
            short8 b2 = *(const short8*)&bT[(32 + r16) * AS + ko];
            short8 b3 = *(const short8*)&bT[(48 + r16) * AS + ko];
            acc[0][0] = __builtin_amdgcn_mfma_f32_16x16x32_bf16(a0, b0, acc[0][0], 0, 0, 0);
            acc[0][1] = __builtin_amdgcn_mfma_f32_16x16x32_bf16(a0, b1, acc[0][1], 0, 0, 0);
            acc[0][2] = __builtin_amdgcn_mfma_f32_16x16x32_bf16(a0, b2, acc[0][2], 0, 0, 0);
            acc[0][3] = __builtin_amdgcn_mfma_f32_16x16x32_bf16(a0, b3, acc[0][3], 0, 0, 0);
            acc[1][0] = __builtin_amdgcn_mfma_f32_16x16x32_bf16(a1, b0, acc[1][0], 0, 0, 0);
            acc[1][1] = __builtin_amdgcn_mfma_f32_16x16x32_bf16(a1, b1, acc[1][1], 0, 0, 0);
            acc[1][2] = __builtin_amdgcn_mfma_f32_16x16x32_bf16(a1, b2, acc[1][2], 0, 0, 0);
            acc[1][3] = __builtin_amdgcn_mfma_f32_16x16x32_bf16(a1, b3, acc[1][3], 0, 0, 0);
        }
    }

    // ---- epilogue: C/D layout col=lane&15, row=(lane>>4)*4+reg ----
    if (!CHILD) __syncthreads();   // about to reuse aT as reduction scratch
    float* sl = (float*)aT;        // [64 co][16 slot][2]
#pragma unroll
    for (int nb = 0; nb < 4; nb++){
        const int co = nb * 16 + r16;
        const float b = bias[co];
        float ps = 0.f, pq = 0.f;
#pragma unroll
        for (int i = 0; i < 2; i++)
#pragma unroll
            for (int rg = 0; rg < 4; rg++){
                int m = mbase + wv * 32 + i * 16 + qd * 4 + rg;
                float v = acc[i][nb][rg] + b;
                if (CHILD) v += skip[(size_t)(m >> 3) * 64 + co];
                out[(size_t)m * 64 + co] = v;
                ps += v; pq += v * v;
            }
        if (!CHILD){
            int slot = wv * 4 + qd;
            sl[(co * 16 + slot) * 2 + 0] = ps;
            sl[(co * 16 + slot) * 2 + 1] = pq;
        }
    }
    if (!CHILD){
        __syncthreads();
        if (tid < 64){
            float s = 0.f, sq = 0.f;
#pragma unroll
            for (int k = 0; k < 16; k++){
                s  += sl[(tid * 16 + k) * 2 + 0];
                sq += sl[(tid * 16 + k) * 2 + 1];
            }
            atomicAdd(&statsAcc[64 + tid], s);        // gn2 per-channel sum
            atomicAdd(&statsAcc[128 + tid], sq);      // gn2 per-channel sumsq
        }
    }
}

// ---------------- h2 = silu(gn2(hf1)) -> bf16 (stats finalized inline) ----------------
__global__ void h2_compute(const float* __restrict__ hf1, const float* __restrict__ stats,
                           const float* __restrict__ gg, const float* __restrict__ gb,
                           ushort* __restrict__ h2){
    int i = blockIdx.x * 256 + threadIdx.x;
    if (i >= M_PTS * C_OUT) return;
    int c = i & (C_OUT - 1);
    int c0 = c & ~1;               // first channel of the 2-channel group
    const float inv = 1.0f / (M_PTS * 2.0f);
    float mu  = (stats[64 + c0] + stats[64 + c0 + 1]) * inv;
    float var = (stats[128 + c0] + stats[128 + c0 + 1]) * inv - mu * mu;
    float rs = rsqrtf(var + EPS);
    float z = (hf1[i] - mu) * rs * gg[c] + gb[c];
    h2[i] = f2bf(silu(z));
}

extern "C" void kernel_launch(void* const* d_in, const int* in_sizes, int n_in,
                              void* d_out, int out_size, void* d_ws, size_t ws_size,
                              hipStream_t stream){
    const float* x   = (const float*)d_in[0];
    const int*   cds = (const int*)  d_in[1];
    const float* g1  = (const float*)d_in[2];
    const float* b1  = (const float*)d_in[3];
    const float* W1  = (const float*)d_in[4];
    const float* bb1 = (const float*)d_in[5];
    const float* g2  = (const float*)d_in[6];
    const float* b2  = (const float*)d_in[7];
    const float* W2  = (const float*)d_in[8];
    const float* bb2 = (const float*)d_in[9];
    const float* Wsk = (const float*)d_in[10];
    const float* bsk = (const float*)d_in[11];
    float* out = (float*)d_out;
    char* ws = (char*)d_ws;

    // workspace layout (256B-aligned offsets)
    float*  stats  = (float*) (ws);               // 192 f32 accumulators
    int*    pg     = (int*)   (ws + 1024);        // 32768 i32 -> ends 132096
    ushort* h      = (ushort*)(ws + 132096);      // N*C bf16   (5,120,000 B)
    ushort* h2     = (ushort*)(ws + 5252096);     // M*CO bf16  (20,480,000 B)
    float*  s      = (float*) (ws + 25732096);    // N*CO f32   (5,120,000 B)
    ushort* Wt1    = (ushort*)(ws + 30852096);    // 27*64*128 bf16 (442,368 B)
    ushort* Wt2    = (ushort*)(ws + 31294464);    // 27*64*64 bf16  (221,184 B)
    // total ws use: ~31.5 MB. hf1 (fp32, M*CO) lives in d_out between conv1 and h2_compute.

    pg_init<<<128, 256, 0, stream>>>(pg, stats);
    pg_scatter<<<(N_PTS + 255) / 256, 256, 0, stream>>>(cds, pg);
    gn1_partial<<<512, 256, 0, stream>>>(x, stats);
    h_compute<<<(N_PTS * C_IN + 255) / 256, 256, 0, stream>>>(x, stats, g1, b1, h);
    wprep<<<(27 * C_IN * 64 + 255) / 256, 256, 0, stream>>>(W1, Wt1, C_IN);
    wprep<<<(27 * C_OUT * 64 + 255) / 256, 256, 0, stream>>>(W2, Wt2, C_OUT);
    skip_kernel<<<N_PTS / 4, 256, 0, stream>>>(x, Wsk, bsk, s);
    conv_mfma<C_IN, 0><<<M_PTS / 128, 256, 0, stream>>>(h, pg, cds, Wt1, bb1, nullptr, out, stats);
    h2_compute<<<(M_PTS * C_OUT + 255) / 256, 256, 0, stream>>>(out, stats, g2, b2, h2);
    conv_mfma<C_OUT, 1><<<M_PTS / 128, 256, 0, stream>>>(h2, pg, cds, Wt2, bb2, s, out, nullptr);
}

// Round 5
// 390.725 us; speedup vs baseline: 8.5969x; 1.0205x over previous
//
#include <hip/hip_runtime.h>
#include <hip/hip_bf16.h>
#include <math.h>

#define N_PTS 20000
#define C_IN 128
#define C_OUT 64
#define M_PTS (N_PTS*8)
#define EPS 1e-5f

typedef __attribute__((ext_vector_type(8))) short short8;
typedef __attribute__((ext_vector_type(4))) float float4v;

__device__ __forceinline__ ushort f2bf(float f){
    unsigned int i = __float_as_uint(f);
    unsigned int r = i + 0x7fffu + ((i >> 16) & 1u);
    return (ushort)(r >> 16);
}
__device__ __forceinline__ float bf2f(ushort u){ return __uint_as_float(((unsigned int)u) << 16); }
__device__ __forceinline__ float silu(float z){ return z / (1.f + expf(-z)); }

// stats layout (fp32, ws): [0..31] gn1 group sum, [32..63] gn1 group sumsq,
//                          [64..127] gn2 ch sum, [128..191] gn2 ch sumsq

// ================= K1: wprep1 + wprep2 + pg_init(+zero rows) + gn1_partial =================
// blocks: [0,864) wprep1, [864,1296) wprep2, [1296,1424) pg_init, [1424,1936) gn1
__global__ void __launch_bounds__(256) prep_kernel(
    const float* __restrict__ W1, const float* __restrict__ W2,
    ushort* __restrict__ Wt1, ushort* __restrict__ Wt2,
    int* __restrict__ pg, ushort* __restrict__ h, ushort* __restrict__ h2,
    const float* __restrict__ x, float* __restrict__ stats)
{
    const int b = blockIdx.x, tid = threadIdx.x;
    if (b < 864){
        // Wt1 fragment order: idx = (((t*4+kb)*4+nb)*64+l)*8+j, KB=4
        int idx = b * 256 + tid;
        int j = idx & 7, l = (idx >> 3) & 63, nb = (idx >> 9) & 3, kb = (idx >> 11) & 3, t = idx >> 13;
        int ci = kb * 32 + (l >> 4) * 8 + j, co = nb * 16 + (l & 15);
        Wt1[idx] = f2bf(W1[(t * C_IN + ci) * 64 + co]);
    } else if (b < 1296){
        // Wt2 fragment order: idx = (((t*2+kb)*4+nb)*64+l)*8+j, KB=2
        int idx = (b - 864) * 256 + tid;
        int j = idx & 7, l = (idx >> 3) & 63, nb = (idx >> 9) & 3, kb = (idx >> 11) & 1, t = idx >> 12;
        int ci = kb * 32 + (l >> 4) * 8 + j, co = nb * 16 + (l & 15);
        Wt2[idx] = f2bf(W2[(t * C_OUT + ci) * 64 + co]);
    } else if (b < 1424){
        int i = (b - 1296) * 256 + tid;
        pg[i] = -1;
        if (b == 1296){
            if (tid < C_IN) h[(size_t)N_PTS * C_IN + tid] = 0;    // zero feature row (conv1)
            if (tid < C_OUT) h2[(size_t)M_PTS * C_OUT + tid] = 0; // zero feature row (conv2)
        }
    } else {
        // gn1 partial: 512 blocks, grid-stride rows, LDS + global atomics
        __shared__ float ls[64];
        if (tid < 64) ls[tid] = 0.f;
        __syncthreads();
        const int g = tid & 31;
        const int r0 = (b - 1424) * 8 + (tid >> 5);
        float sum = 0.f, sq = 0.f;
        for (int r = r0; r < N_PTS; r += 4096){
            float4 v = *(const float4*)(x + (size_t)r * C_IN + g * 4);
            sum += v.x + v.y + v.z + v.w;
            sq  += v.x*v.x + v.y*v.y + v.z*v.z + v.w*v.w;
        }
        atomicAdd(&ls[g], sum);
        atomicAdd(&ls[32 + g], sq);
        __syncthreads();
        if (tid < 64) atomicAdd(&stats[tid], ls[tid]);
    }
}

// ================= K2: pg_scatter + h_compute + skip =================
// blocks: [0,79) scatter, [79,2579) h (vec4), [2579,7579) skip
__global__ void __launch_bounds__(256) mid_kernel(
    const int* __restrict__ cds, int* __restrict__ pg,
    const float* __restrict__ x, const float* __restrict__ stats,
    const float* __restrict__ g1, const float* __restrict__ b1, ushort* __restrict__ h,
    const float* __restrict__ Wsk, const float* __restrict__ bsk, float* __restrict__ s)
{
    __shared__ float w[C_IN * C_OUT];
    const int b = blockIdx.x, tid = threadIdx.x;
    if (b < 79){
        int i = b * 256 + tid;
        if (i < N_PTS){
            const int* cd = cds + i * 4;
            pg[(cd[1] * 32 + cd[2]) * 32 + cd[3]] = i;
        }
    } else if (b < 2579){
        int i = ((b - 79) * 256 + tid) * 4;
        int c0 = i & (C_IN - 1);                  // multiple of 4 -> one group
        int g = c0 >> 2;
        float mu = stats[g] * (1.0f / (N_PTS * 4.0f));
        float var = stats[32 + g] * (1.0f / (N_PTS * 4.0f)) - mu * mu;
        float rs = rsqrtf(var + EPS);
        float4 v = *(const float4*)(x + i);
        ushort4 o;
        o.x = f2bf(silu((v.x - mu) * rs * g1[c0+0] + b1[c0+0]));
        o.y = f2bf(silu((v.y - mu) * rs * g1[c0+1] + b1[c0+1]));
        o.z = f2bf(silu((v.z - mu) * rs * g1[c0+2] + b1[c0+2]));
        o.w = f2bf(silu((v.w - mu) * rs * g1[c0+3] + b1[c0+3]));
        *(ushort4*)(h + i) = o;
    } else {
        for (int j = tid; j < C_IN * C_OUT; j += 256) w[j] = Wsk[j];
        __syncthreads();
        int co = tid & 63, pr = tid >> 6;
        int p = (b - 2579) * 4 + pr;
        const float* xr = x + (size_t)p * C_IN;
        float a = bsk[co];
        for (int cb = 0; cb < C_IN; cb += 4){
            float4 v = *(const float4*)(xr + cb);
            a += v.x * w[(cb+0)*64+co] + v.y * w[(cb+1)*64+co]
               + v.z * w[(cb+2)*64+co] + v.w * w[(cb+3)*64+co];
        }
        s[(size_t)p * C_OUT + co] = a;
    }
}

// ================= conv: direct-global implicit GEMM, no LDS =================
// block = 1 wave (64 threads), M-tile 64 children, N = 64.
// A-frags: scattered 16B global loads from gathered rows (zero-row for missing).
// B-frags: coalesced 1KB wave loads from fragment-ordered Wt.
// CHILD=0 (conv1): feat row = parent (row>>3); writes hf1 bf16; fused GN2 sums.
// CHILD=1 (conv2): feat row = child; adds skip; writes fp32 out.
template<int CIN, int CHILD>
__global__ void __launch_bounds__(64, 3) conv_direct(
    const ushort* __restrict__ feat, const int* __restrict__ pg,
    const int* __restrict__ coords, const ushort* __restrict__ Wt,
    const float* __restrict__ bias, const float* __restrict__ skip,
    ushort* __restrict__ hf1_bf, float* __restrict__ out, float* __restrict__ statsAcc)
{
    constexpr int KB = CIN / 32;
    __shared__ int rws[64];
    const int l = threadIdx.x;
    const int r16 = l & 15, qd = l >> 4;
    const int mb = blockIdx.x * 64;

    // this lane's child coords
    int cx0, cy0, cz0;
    {
        int m = mb + l, p = m >> 3, o = m & 7;
        cx0 = 2 * coords[p*4+1] + ((o >> 2) & 1);
        cy0 = 2 * coords[p*4+2] + ((o >> 1) & 1);
        cz0 = 2 * coords[p*4+3] + (o & 1);
    }

    float4v acc[4][4];
#pragma unroll
    for (int rb = 0; rb < 4; rb++)
#pragma unroll
        for (int nb = 0; nb < 4; nb++)
#pragma unroll
            for (int rg = 0; rg < 4; rg++) acc[rb][nb][rg] = 0.f;

    for (int t = 0; t < 27; t++){
        const int dx = t / 9 - 1, dy = (t / 3) % 3 - 1, dz = t % 3 - 1;
        const int cx = cx0 + dx, cy = cy0 + dy, cz = cz0 + dz;
        int row = 8 * N_PTS;                       // zero row (child-space)
        if ((unsigned)cx < 64u && (unsigned)cy < 64u && (unsigned)cz < 64u){
            int pidx = pg[((cx >> 1) * 32 + (cy >> 1)) * 32 + (cz >> 1)];
            if (pidx >= 0) row = pidx * 8 + (((cx & 1) << 2) | ((cy & 1) << 1) | (cz & 1));
        }
        rws[l] = row;
        __syncthreads();
        int fr0 = rws[r16], fr1 = rws[16 + r16], fr2 = rws[32 + r16], fr3 = rws[48 + r16];
        if (!CHILD){ fr0 >>= 3; fr1 >>= 3; fr2 >>= 3; fr3 >>= 3; }
        const ushort* a0 = feat + (size_t)fr0 * CIN + qd * 8;
        const ushort* a1 = feat + (size_t)fr1 * CIN + qd * 8;
        const ushort* a2 = feat + (size_t)fr2 * CIN + qd * 8;
        const ushort* a3 = feat + (size_t)fr3 * CIN + qd * 8;
        const ushort* wt = Wt + (size_t)t * (KB * 2048) + l * 8;
#pragma unroll
        for (int kb = 0; kb < KB; kb++){
            short8 b0 = *(const short8*)(wt + (kb*4+0)*512);
            short8 b1 = *(const short8*)(wt + (kb*4+1)*512);
            short8 b2 = *(const short8*)(wt + (kb*4+2)*512);
            short8 b3 = *(const short8*)(wt + (kb*4+3)*512);
            short8 av0 = *(const short8*)(a0 + kb*32);
            short8 av1 = *(const short8*)(a1 + kb*32);
            short8 av2 = *(const short8*)(a2 + kb*32);
            short8 av3 = *(const short8*)(a3 + kb*32);
            acc[0][0] = __builtin_amdgcn_mfma_f32_16x16x32_bf16(av0, b0, acc[0][0], 0, 0, 0);
            acc[0][1] = __builtin_amdgcn_mfma_f32_16x16x32_bf16(av0, b1, acc[0][1], 0, 0, 0);
            acc[0][2] = __builtin_amdgcn_mfma_f32_16x16x32_bf16(av0, b2, acc[0][2], 0, 0, 0);
            acc[0][3] = __builtin_amdgcn_mfma_f32_16x16x32_bf16(av0, b3, acc[0][3], 0, 0, 0);
            acc[1][0] = __builtin_amdgcn_mfma_f32_16x16x32_bf16(av1, b0, acc[1][0], 0, 0, 0);
            acc[1][1] = __builtin_amdgcn_mfma_f32_16x16x32_bf16(av1, b1, acc[1][1], 0, 0, 0);
            acc[1][2] = __builtin_amdgcn_mfma_f32_16x16x32_bf16(av1, b2, acc[1][2], 0, 0, 0);
            acc[1][3] = __builtin_amdgcn_mfma_f32_16x16x32_bf16(av1, b3, acc[1][3], 0, 0, 0);
            acc[2][0] = __builtin_amdgcn_mfma_f32_16x16x32_bf16(av2, b0, acc[2][0], 0, 0, 0);
            acc[2][1] = __builtin_amdgcn_mfma_f32_16x16x32_bf16(av2, b1, acc[2][1], 0, 0, 0);
            acc[2][2] = __builtin_amdgcn_mfma_f32_16x16x32_bf16(av2, b2, acc[2][2], 0, 0, 0);
            acc[2][3] = __builtin_amdgcn_mfma_f32_16x16x32_bf16(av2, b3, acc[2][3], 0, 0, 0);
            acc[3][0] = __builtin_amdgcn_mfma_f32_16x16x32_bf16(av3, b0, acc[3][0], 0, 0, 0);
            acc[3][1] = __builtin_amdgcn_mfma_f32_16x16x32_bf16(av3, b1, acc[3][1], 0, 0, 0);
            acc[3][2] = __builtin_amdgcn_mfma_f32_16x16x32_bf16(av3, b2, acc[3][2], 0, 0, 0);
            acc[3][3] = __builtin_amdgcn_mfma_f32_16x16x32_bf16(av3, b3, acc[3][3], 0, 0, 0);
        }
    }

    // epilogue: C/D layout col = lane&15, row = (lane>>4)*4 + reg
    float bsv[4] = { bias[r16], bias[16 + r16], bias[32 + r16], bias[48 + r16] };
    if (!CHILD){
        float ps[4] = {0,0,0,0}, pq[4] = {0,0,0,0};
#pragma unroll
        for (int rb = 0; rb < 4; rb++)
#pragma unroll
            for (int nb = 0; nb < 4; nb++)
#pragma unroll
                for (int rg = 0; rg < 4; rg++){
                    int mm = mb + rb * 16 + qd * 4 + rg;
                    float v = acc[rb][nb][rg] + bsv[nb];
                    hf1_bf[(size_t)mm * 64 + nb * 16 + r16] = f2bf(v);
                    ps[nb] += v; pq[nb] += v * v;
                }
#pragma unroll
        for (int nb = 0; nb < 4; nb++){
            float s1 = ps[nb], s2 = pq[nb];
            s1 += __shfl_xor(s1, 16, 64); s2 += __shfl_xor(s2, 16, 64);
            s1 += __shfl_xor(s1, 32, 64); s2 += __shfl_xor(s2, 32, 64);
            if (qd == 0){
                atomicAdd(&statsAcc[64 + nb * 16 + r16], s1);
                atomicAdd(&statsAcc[128 + nb * 16 + r16], s2);
            }
        }
    } else {
#pragma unroll
        for (int rb = 0; rb < 4; rb++)
#pragma unroll
            for (int rg = 0; rg < 4; rg++){
                int mm = mb + rb * 16 + qd * 4 + rg;
                const float* sk = skip + (size_t)(mm >> 3) * 64;
#pragma unroll
                for (int nb = 0; nb < 4; nb++){
                    int co = nb * 16 + r16;
                    out[(size_t)mm * 64 + co] = acc[rb][nb][rg] + bsv[nb] + sk[co];
                }
            }
    }
}

// ================= K4: h2 = silu(gn2(hf1_bf16)) -> bf16 =================
__global__ void __launch_bounds__(256) h2_kernel(
    const ushort* __restrict__ hf1, const float* __restrict__ stats,
    const float* __restrict__ gg, const float* __restrict__ gb, ushort* __restrict__ h2)
{
    int i = (blockIdx.x * 256 + threadIdx.x) * 4;
    if (i >= M_PTS * C_OUT) return;
    int c0 = i & (C_OUT - 1);                    // multiple of 4
    const float inv = 1.0f / (M_PTS * 2.0f);
    float muA = (stats[64 + c0] + stats[64 + c0 + 1]) * inv;
    float vA  = (stats[128 + c0] + stats[128 + c0 + 1]) * inv - muA * muA;
    float rsA = rsqrtf(vA + EPS);
    float muB = (stats[64 + c0 + 2] + stats[64 + c0 + 3]) * inv;
    float vB  = (stats[128 + c0 + 2] + stats[128 + c0 + 3]) * inv - muB * muB;
    float rsB = rsqrtf(vB + EPS);
    ushort4 u = *(const ushort4*)(hf1 + i);
    ushort4 o;
    o.x = f2bf(silu((bf2f(u.x) - muA) * rsA * gg[c0+0] + gb[c0+0]));
    o.y = f2bf(silu((bf2f(u.y) - muA) * rsA * gg[c0+1] + gb[c0+1]));
    o.z = f2bf(silu((bf2f(u.z) - muB) * rsB * gg[c0+2] + gb[c0+2]));
    o.w = f2bf(silu((bf2f(u.w) - muB) * rsB * gg[c0+3] + gb[c0+3]));
    *(ushort4*)(h2 + i) = o;
}

extern "C" void kernel_launch(void* const* d_in, const int* in_sizes, int n_in,
                              void* d_out, int out_size, void* d_ws, size_t ws_size,
                              hipStream_t stream){
    const float* x   = (const float*)d_in[0];
    const int*   cds = (const int*)  d_in[1];
    const float* g1  = (const float*)d_in[2];
    const float* b1  = (const float*)d_in[3];
    const float* W1  = (const float*)d_in[4];
    const float* bb1 = (const float*)d_in[5];
    const float* g2  = (const float*)d_in[6];
    const float* b2  = (const float*)d_in[7];
    const float* W2  = (const float*)d_in[8];
    const float* bb2 = (const float*)d_in[9];
    const float* Wsk = (const float*)d_in[10];
    const float* bsk = (const float*)d_in[11];
    float* out = (float*)d_out;
    char* ws = (char*)d_ws;

    // workspace layout (16B-aligned)
    float*  stats = (float*) (ws);                 // 192 f32 (zeroed via memsetAsync)
    int*    pg    = (int*)   (ws + 1024);          // 131072 B -> 132096
    ushort* h     = (ushort*)(ws + 132096);        // (N+1)*128 bf16 = 5,120,256 -> 5,252,352
    ushort* h2    = (ushort*)(ws + 5252352);       // (M+1)*64 bf16 = 20,480,128 -> 25,732,480
    float*  s     = (float*) (ws + 25732480);      // N*64 f32 = 5,120,000 -> 30,852,480
    ushort* Wt1   = (ushort*)(ws + 30852480);      // 442,368 -> 31,294,848
    ushort* Wt2   = (ushort*)(ws + 31294848);      // 221,184 -> 31,516,032
    // hf1 (bf16, M*64) lives in d_out between conv1 and h2_kernel; conv2 overwrites d_out as f32.

    hipMemsetAsync(stats, 0, 192 * sizeof(float), stream);
    prep_kernel<<<1936, 256, 0, stream>>>(W1, W2, Wt1, Wt2, pg, h, h2, x, stats);
    mid_kernel<<<7579, 256, 0, stream>>>(cds, pg, x, stats, g1, b1, h, Wsk, bsk, s);
    conv_direct<C_IN, 0><<<2500, 64, 0, stream>>>(h, pg, cds, Wt1, bb1, nullptr,
                                                  (ushort*)d_out, nullptr, stats);
    h2_kernel<<<12500, 256, 0, stream>>>((const ushort*)d_out, stats, g2, b2, h2);
    conv_direct<C_OUT, 1><<<2500, 64, 0, stream>>>(h2, pg, cds, Wt2, bb2, s,
                                                   nullptr, out, nullptr);
}